// Round 1
// baseline (2036.680 us; speedup 1.0000x reference)
//
#include <hip/hip_runtime.h>
#include <hip/hip_bf16.h>
#include <math.h>

#define N_NODES 100000
#define N_EDGES 1600000
#define F_IN 512
#define HID 128
#define NCLS 40

// ---------------- degree / normalization ----------------

__global__ void k_init_deg(float* deg, int n) {
    int i = blockIdx.x * blockDim.x + threadIdx.x;
    if (i < n) deg[i] = 1.0f;  // self loop
}

__global__ void k_count_deg(const int* __restrict__ dst, float* deg, int e) {
    int i = blockIdx.x * blockDim.x + threadIdx.x;
    if (i < e) atomicAdd(&deg[dst[i]], 1.0f);
}

__global__ void k_rsqrt(float* deg, int n) {
    int i = blockIdx.x * blockDim.x + threadIdx.x;
    if (i < n) deg[i] = rsqrtf(deg[i]);   // in-place: deg -> inv_sqrt
}

// ---------------- GEMM1: h1 = x @ W1  [N,512]x[512,128] ----------------
// 64x128 tile per block, BK=32, 256 threads, 8x4 microtile.

#define BM 64
#define BK 32
#define BN 128

__global__ __launch_bounds__(256) void k_gemm1(
    const float* __restrict__ A,   // [M,512]
    const float* __restrict__ B,   // [512,128]
    float* __restrict__ C,         // [M,128]
    int M)
{
    __shared__ float As[BK][BM + 1];   // k-major, padded
    __shared__ float Bs[BK][BN];

    const int tid = threadIdx.x;
    const int block_m = blockIdx.x * BM;
    const int tn = tid & 31;   // 32 groups along N, 4 cols each
    const int tm = tid >> 5;   // 8 groups along M, 8 rows each

    float acc[8][4];
    #pragma unroll
    for (int m = 0; m < 8; ++m)
        #pragma unroll
        for (int n = 0; n < 4; ++n) acc[m][n] = 0.f;

    for (int k0 = 0; k0 < F_IN; k0 += BK) {
        // A tile: 64 rows x 32 k  (2048 floats, 8 per thread)
        #pragma unroll
        for (int i = 0; i < 8; ++i) {
            int flat = tid + 256 * i;
            int r = flat >> 5, kk = flat & 31;
            int gr = block_m + r;
            float v = (gr < M) ? A[(long long)gr * F_IN + k0 + kk] : 0.f;
            As[kk][r] = v;
        }
        // B tile: 32 k x 128 n (4096 floats, 16 per thread)
        #pragma unroll
        for (int i = 0; i < 16; ++i) {
            int flat = tid + 256 * i;
            int kk = flat >> 7, nn = flat & 127;
            Bs[kk][nn] = B[(k0 + kk) * BN + nn];
        }
        __syncthreads();

        #pragma unroll
        for (int kk = 0; kk < BK; ++kk) {
            float a[8], b[4];
            #pragma unroll
            for (int m = 0; m < 8; ++m) a[m] = As[kk][tm * 8 + m];
            #pragma unroll
            for (int n = 0; n < 4; ++n) b[n] = Bs[kk][tn * 4 + n];
            #pragma unroll
            for (int m = 0; m < 8; ++m)
                #pragma unroll
                for (int n = 0; n < 4; ++n) acc[m][n] += a[m] * b[n];
        }
        __syncthreads();
    }

    #pragma unroll
    for (int m = 0; m < 8; ++m) {
        int gr = block_m + tm * 8 + m;
        if (gr < M) {
            #pragma unroll
            for (int n = 0; n < 4; ++n)
                C[(long long)gr * BN + tn * 4 + n] = acc[m][n];
        }
    }
}

// ---------------- layer-1 aggregation ----------------

// agg[i][j] = h1[i][j] * inv[i]^2   (self-loop init)
__global__ void k_self1(const float* __restrict__ h, const float* __restrict__ inv,
                        float* __restrict__ agg, int total) {
    int idx = blockIdx.x * blockDim.x + threadIdx.x;
    if (idx >= total) return;
    int i = idx >> 7;
    float is = inv[i];
    agg[idx] = h[idx] * is * is;
}

// one thread per (edge, feature): atomicAdd
__global__ void k_scatter1(const int* __restrict__ src, const int* __restrict__ dst,
                           const float* __restrict__ inv, const float* __restrict__ h,
                           float* __restrict__ agg) {
    unsigned gid = blockIdx.x * blockDim.x + threadIdx.x;   // < E*128 = 204.8M
    unsigned e = gid >> 7;
    unsigned j = gid & 127;
    int s = src[e], d = dst[e];
    float c = inv[s] * inv[d];
    atomicAdd(&agg[(unsigned)d * HID + j], h[(unsigned)s * HID + j] * c);
}

// out[idx] = relu(agg[idx] + b1[j])
__global__ void k_relu_bias(const float* __restrict__ agg, const float* __restrict__ b,
                            float* __restrict__ out, int total) {
    int idx = blockIdx.x * blockDim.x + threadIdx.x;
    if (idx >= total) return;
    float v = agg[idx] + b[idx & 127];
    out[idx] = v > 0.f ? v : 0.f;
}

// ---------------- GEMM2: h2 = relu_out @ W2  [N,128]x[128,40] ----------------

__global__ __launch_bounds__(256) void k_gemm2(
    const float* __restrict__ H, const float* __restrict__ W,
    float* __restrict__ OUT, int total)
{
    __shared__ float Ws[HID * NCLS];   // 20 KiB
    for (int i = threadIdx.x; i < HID * NCLS; i += 256) Ws[i] = W[i];
    __syncthreads();
    int idx = blockIdx.x * blockDim.x + threadIdx.x;
    if (idx >= total) return;
    unsigned node = (unsigned)idx / NCLS;
    unsigned j = (unsigned)idx - node * NCLS;
    const float* hrow = H + (long long)node * HID;
    float acc = 0.f;
    #pragma unroll 8
    for (int k = 0; k < HID; ++k) acc += hrow[k] * Ws[k * NCLS + j];
    OUT[idx] = acc;
}

// ---------------- layer-2 aggregation (into d_out) ----------------

// out[i][j] = h2[i][j]*inv[i]^2 + b2[j]
__global__ void k_self2(const float* __restrict__ h2, const float* __restrict__ inv,
                        const float* __restrict__ b, float* __restrict__ out, int total) {
    int idx = blockIdx.x * blockDim.x + threadIdx.x;
    if (idx >= total) return;
    unsigned node = (unsigned)idx / NCLS;
    unsigned j = (unsigned)idx - node * NCLS;
    float is = inv[node];
    out[idx] = h2[idx] * is * is + b[j];
}

// lane j<40 of each wave handles one feature of one edge
__global__ void k_scatter2(const int* __restrict__ src, const int* __restrict__ dst,
                           const float* __restrict__ inv, const float* __restrict__ h2,
                           float* __restrict__ out) {
    unsigned gid = blockIdx.x * blockDim.x + threadIdx.x;   // < E*64
    unsigned e = gid >> 6;
    unsigned j = gid & 63;
    if (j >= NCLS) return;
    int s = src[e], d = dst[e];
    float c = inv[s] * inv[d];
    atomicAdd(&out[(unsigned)d * NCLS + j], h2[(unsigned)s * NCLS + j] * c);
}

// ---------------- log_softmax over 40 classes, one wave per node ----------------

__global__ __launch_bounds__(256) void k_logsm(float* __restrict__ out, int n) {
    int wave = threadIdx.x >> 6;
    int lane = threadIdx.x & 63;
    int node = blockIdx.x * 4 + wave;
    if (node >= n) return;
    float v = (lane < NCLS) ? out[(long long)node * NCLS + lane] : -INFINITY;
    float m = v;
    #pragma unroll
    for (int off = 32; off; off >>= 1) m = fmaxf(m, __shfl_down(m, off));
    m = __shfl(m, 0);
    float ex = (lane < NCLS) ? __expf(v - m) : 0.f;
    float s = ex;
    #pragma unroll
    for (int off = 32; off; off >>= 1) s += __shfl_down(s, off);
    s = __shfl(s, 0);
    if (lane < NCLS) out[(long long)node * NCLS + lane] = v - m - __logf(s);
}

// ---------------- launch ----------------

extern "C" void kernel_launch(void* const* d_in, const int* in_sizes, int n_in,
                              void* d_out, int out_size, void* d_ws, size_t ws_size,
                              hipStream_t stream) {
    const float* x   = (const float*)d_in[0];
    const int*   ei  = (const int*)d_in[1];
    const float* W1  = (const float*)d_in[2];
    const float* b1  = (const float*)d_in[3];
    const float* W2  = (const float*)d_in[4];
    const float* b2  = (const float*)d_in[5];
    float* out = (float*)d_out;

    const int* src = ei;
    const int* dst = ei + N_EDGES;

    // workspace layout (floats)
    float* ws = (float*)d_ws;
    float* inv  = ws;                              // N_NODES (pad to 131072)
    float* h1   = ws + 131072;                     // N*128 = 12.8M
    float* agg1 = h1 + (size_t)N_NODES * HID;      // 12.8M
    float* h2   = agg1 + (size_t)N_NODES * HID;    // N*40 = 4M
    // d_out doubles as agg2

    const int T = 256;

    // normalization coefficients
    k_init_deg<<<(N_NODES + T - 1) / T, T, 0, stream>>>(inv, N_NODES);
    k_count_deg<<<N_EDGES / T, T, 0, stream>>>(dst, inv, N_EDGES);
    k_rsqrt<<<(N_NODES + T - 1) / T, T, 0, stream>>>(inv, N_NODES);

    // layer 1
    k_gemm1<<<(N_NODES + BM - 1) / BM, T, 0, stream>>>(x, W1, h1, N_NODES);
    k_self1<<<(N_NODES * HID) / T, T, 0, stream>>>(h1, inv, agg1, N_NODES * HID);
    k_scatter1<<<(N_EDGES * 128u) / T, T, 0, stream>>>(src, dst, inv, h1, agg1);
    k_relu_bias<<<(N_NODES * HID) / T, T, 0, stream>>>(agg1, b1, h1, N_NODES * HID);

    // layer 2
    k_gemm2<<<(N_NODES * NCLS + T - 1) / T, T, 0, stream>>>(h1, W2, h2, N_NODES * NCLS);
    k_self2<<<(N_NODES * NCLS + T - 1) / T, T, 0, stream>>>(h2, inv, b2, out, N_NODES * NCLS);
    k_scatter2<<<(N_EDGES * 64u) / T, T, 0, stream>>>(src, dst, inv, h2, out);

    // log_softmax
    k_logsm<<<(N_NODES + 3) / 4, T, 0, stream>>>(out, N_NODES);
}

// Round 2
// 1379.605 us; speedup vs baseline: 1.4763x; 1.4763x over previous
//
#include <hip/hip_runtime.h>
#include <hip/hip_bf16.h>
#include <math.h>

#define N_NODES 100000
#define N_EDGES 1600000
#define F_IN 512
#define HID 128
#define NCLS 40

// ---------------- utility ----------------

__global__ void k_zero_int(int* p, int n) {
    int i = blockIdx.x * blockDim.x + threadIdx.x;
    if (i < n) p[i] = 0;
}

// ---------------- degree / normalization ----------------

__global__ void k_count_deg(const int* __restrict__ dst, int* __restrict__ deg, int e) {
    int i = blockIdx.x * blockDim.x + threadIdx.x;
    if (i < e) atomicAdd(&deg[dst[i]], 1);
}

__global__ void k_inv(const int* __restrict__ deg, float* __restrict__ inv, int n) {
    int i = blockIdx.x * blockDim.x + threadIdx.x;
    if (i < n) inv[i] = rsqrtf((float)deg[i] + 1.0f);   // +1 self loop
}

// ---------------- exclusive scan (3-kernel) ----------------

#define SCAN_B 256

__global__ __launch_bounds__(SCAN_B) void k_scan1(const int* __restrict__ deg,
                                                  int* __restrict__ rp,
                                                  int* __restrict__ bsums, int n) {
    __shared__ int s[SCAN_B];
    int tid = threadIdx.x;
    int i = blockIdx.x * SCAN_B + tid;
    int v = (i < n) ? deg[i] : 0;
    s[tid] = v;
    __syncthreads();
    for (int off = 1; off < SCAN_B; off <<= 1) {
        int t = (tid >= off) ? s[tid - off] : 0;
        __syncthreads();
        s[tid] += t;
        __syncthreads();
    }
    if (i < n) rp[i] = s[tid] - v;                 // exclusive
    if (tid == SCAN_B - 1) bsums[blockIdx.x] = s[tid];
}

__global__ __launch_bounds__(512) void k_scan2(int* __restrict__ bsums, int nb) {
    __shared__ int s[512];
    int tid = threadIdx.x;
    int v = (tid < nb) ? bsums[tid] : 0;
    s[tid] = v;
    __syncthreads();
    for (int off = 1; off < 512; off <<= 1) {
        int t = (tid >= off) ? s[tid - off] : 0;
        __syncthreads();
        s[tid] += t;
        __syncthreads();
    }
    if (tid < nb) bsums[tid] = s[tid] - v;         // exclusive block offsets
}

__global__ void k_scan3(int* __restrict__ rp, const int* __restrict__ bsums, int n) {
    int i = blockIdx.x * SCAN_B + threadIdx.x;
    if (i < n) rp[i] += bsums[blockIdx.x];
}

// ---------------- CSR fill (counting sort by dst) ----------------

__global__ void k_fill(const int* __restrict__ src, const int* __restrict__ dst,
                       const int* __restrict__ rp, int* __restrict__ cursor,
                       int* __restrict__ csr_src, int e) {
    int i = blockIdx.x * blockDim.x + threadIdx.x;
    if (i >= e) return;
    int d = dst[i];
    int pos = atomicAdd(&cursor[d], 1);
    csr_src[rp[d] + pos] = src[i];
}

// ---------------- GEMM1: h1 = x @ W1  [N,512]x[512,128] ----------------

#define BM 64
#define BK 32
#define BN 128

__global__ __launch_bounds__(256) void k_gemm1(
    const float* __restrict__ A, const float* __restrict__ B,
    float* __restrict__ C, int M)
{
    __shared__ float As[BK][BM + 1];
    __shared__ float Bs[BK][BN];

    const int tid = threadIdx.x;
    const int block_m = blockIdx.x * BM;
    const int tn = tid & 31;
    const int tm = tid >> 5;

    float acc[8][4];
    #pragma unroll
    for (int m = 0; m < 8; ++m)
        #pragma unroll
        for (int n = 0; n < 4; ++n) acc[m][n] = 0.f;

    for (int k0 = 0; k0 < F_IN; k0 += BK) {
        #pragma unroll
        for (int i = 0; i < 8; ++i) {
            int flat = tid + 256 * i;
            int r = flat >> 5, kk = flat & 31;
            int gr = block_m + r;
            float v = (gr < M) ? A[(long long)gr * F_IN + k0 + kk] : 0.f;
            As[kk][r] = v;
        }
        #pragma unroll
        for (int i = 0; i < 16; ++i) {
            int flat = tid + 256 * i;
            int kk = flat >> 7, nn = flat & 127;
            Bs[kk][nn] = B[(k0 + kk) * BN + nn];
        }
        __syncthreads();

        #pragma unroll
        for (int kk = 0; kk < BK; ++kk) {
            float a[8], b[4];
            #pragma unroll
            for (int m = 0; m < 8; ++m) a[m] = As[kk][tm * 8 + m];
            #pragma unroll
            for (int n = 0; n < 4; ++n) b[n] = Bs[kk][tn * 4 + n];
            #pragma unroll
            for (int m = 0; m < 8; ++m)
                #pragma unroll
                for (int n = 0; n < 4; ++n) acc[m][n] += a[m] * b[n];
        }
        __syncthreads();
    }

    #pragma unroll
    for (int m = 0; m < 8; ++m) {
        int gr = block_m + tm * 8 + m;
        if (gr < M) {
            #pragma unroll
            for (int n = 0; n < 4; ++n)
                C[(long long)gr * BN + tn * 4 + n] = acc[m][n];
        }
    }
}

// ---------------- gather aggregation, layer 1 (fused self + bias + relu) ------
// one block of 128 threads per node; thread j = feature j

__global__ __launch_bounds__(128) void k_gather1(
    const float* __restrict__ h, const int* __restrict__ rp,
    const int* __restrict__ deg, const float* __restrict__ inv,
    const int* __restrict__ csr_src, const float* __restrict__ b1,
    float* __restrict__ out)
{
    __shared__ int   s_src[64];
    __shared__ float s_inv[64];
    const int node = blockIdx.x;
    const int j = threadIdx.x;
    const int start = rp[node];
    const int cnt = deg[node];

    float acc = 0.f;
    for (int base = 0; base < cnt; base += 64) {
        int m = min(64, cnt - base);
        __syncthreads();
        if (j < m) {
            int s = csr_src[start + base + j];
            s_src[j] = s;
            s_inv[j] = inv[s];
        }
        __syncthreads();
        for (int t = 0; t < m; ++t)
            acc += h[(size_t)s_src[t] * HID + j] * s_inv[t];
    }
    float invd = inv[node];
    float v = acc * invd + h[(size_t)node * HID + j] * invd * invd + b1[j];
    out[(size_t)node * HID + j] = fmaxf(v, 0.f);
}

// ---------------- GEMM2: h2 = hrelu @ W2  [N,128]x[128,40] ----------------

__global__ __launch_bounds__(256) void k_gemm2(
    const float* __restrict__ H, const float* __restrict__ W,
    float* __restrict__ OUT, int total)
{
    __shared__ float Ws[HID * NCLS];
    for (int i = threadIdx.x; i < HID * NCLS; i += 256) Ws[i] = W[i];
    __syncthreads();
    int idx = blockIdx.x * blockDim.x + threadIdx.x;
    if (idx >= total) return;
    unsigned node = (unsigned)idx / NCLS;
    unsigned j = (unsigned)idx - node * NCLS;
    const float* hrow = H + (long long)node * HID;
    float acc = 0.f;
    #pragma unroll 8
    for (int k = 0; k < HID; ++k) acc += hrow[k] * Ws[k * NCLS + j];
    OUT[idx] = acc;
}

// ------- gather aggregation, layer 2 (fused self + bias + log_softmax) -------
// one wave per node (grid*4 == N exactly); lane < 40 = class

__global__ __launch_bounds__(256) void k_gather2(
    const float* __restrict__ h2, const int* __restrict__ rp,
    const int* __restrict__ deg, const float* __restrict__ inv,
    const int* __restrict__ csr_src, const float* __restrict__ b2,
    float* __restrict__ out)
{
    const int wave = threadIdx.x >> 6;
    const int lane = threadIdx.x & 63;
    const int node = blockIdx.x * 4 + wave;   // N divisible by 4: no remainder
    const int start = rp[node];
    const int cnt = deg[node];
    const int j = lane;

    float acc = 0.f;
    for (int t = 0; t < cnt; ++t) {
        int s = csr_src[start + t];
        float c = inv[s];
        if (j < NCLS) acc += h2[(size_t)s * NCLS + j] * c;
    }
    float invd = inv[node];
    float v;
    if (j < NCLS)
        v = acc * invd + h2[(size_t)node * NCLS + j] * invd * invd + b2[j];
    else
        v = -INFINITY;

    float m = v;
    #pragma unroll
    for (int off = 32; off; off >>= 1) m = fmaxf(m, __shfl_down(m, off));
    m = __shfl(m, 0);
    float ex = (j < NCLS) ? __expf(v - m) : 0.f;
    float s2 = ex;
    #pragma unroll
    for (int off = 32; off; off >>= 1) s2 += __shfl_down(s2, off);
    s2 = __shfl(s2, 0);
    if (j < NCLS) out[(size_t)node * NCLS + j] = v - m - __logf(s2);
}

// ---------------- launch ----------------

extern "C" void kernel_launch(void* const* d_in, const int* in_sizes, int n_in,
                              void* d_out, int out_size, void* d_ws, size_t ws_size,
                              hipStream_t stream) {
    const float* x   = (const float*)d_in[0];
    const int*   ei  = (const int*)d_in[1];
    const float* W1  = (const float*)d_in[2];
    const float* b1  = (const float*)d_in[3];
    const float* W2  = (const float*)d_in[4];
    const float* b2  = (const float*)d_in[5];
    float* out = (float*)d_out;

    const int* src = ei;
    const int* dst = ei + N_EDGES;

    // workspace layout (4-byte units)
    char* wsb = (char*)d_ws;
    float* inv     = (float*)wsb;                                   // 131072
    float* h1      = inv + 131072;                                  // 12.8M  (reused for h2)
    float* hrelu   = h1 + (size_t)N_NODES * HID;                    // 12.8M
    int*   deg     = (int*)(hrelu + (size_t)N_NODES * HID);         // 131072
    int*   rp      = deg + 131072;                                  // 131072
    int*   cursor  = rp + 131072;                                   // 131072
    int*   bsums   = cursor + 131072;                               // 1024
    int*   csr_src = bsums + 1024;                                  // 1.6M
    float* h2      = h1;                                            // alias (N*40)

    const int T = 256;
    const int NB = (N_NODES + SCAN_B - 1) / SCAN_B;   // 391

    // degree + normalization
    k_zero_int<<<(131072 * 2) / T, T, 0, stream>>>(deg, 131072 * 2);  // deg + rp contiguous; rp overwritten anyway
    k_zero_int<<<131072 / T, T, 0, stream>>>(cursor, 131072);
    k_count_deg<<<N_EDGES / T, T, 0, stream>>>(dst, deg, N_EDGES);
    k_inv<<<NB, SCAN_B, 0, stream>>>(deg, inv, N_NODES);

    // CSR build
    k_scan1<<<NB, SCAN_B, 0, stream>>>(deg, rp, bsums, N_NODES);
    k_scan2<<<1, 512, 0, stream>>>(bsums, NB);
    k_scan3<<<NB, SCAN_B, 0, stream>>>(rp, bsums, N_NODES);
    k_fill<<<N_EDGES / T, T, 0, stream>>>(src, dst, rp, cursor, csr_src, N_EDGES);

    // layer 1
    k_gemm1<<<(N_NODES + BM - 1) / BM, T, 0, stream>>>(x, W1, h1, N_NODES);
    k_gather1<<<N_NODES, 128, 0, stream>>>(h1, rp, deg, inv, csr_src, b1, hrelu);

    // layer 2 (h2 aliases h1 — h1 dead after gather1)
    k_gemm2<<<(N_NODES * NCLS + T - 1) / T, T, 0, stream>>>(hrelu, W2, h2, N_NODES * NCLS);
    k_gather2<<<N_NODES / 4, T, 0, stream>>>(h2, rp, deg, inv, csr_src, b2, out);
}

// Round 3
// 843.704 us; speedup vs baseline: 2.4140x; 1.6352x over previous
//
#include <hip/hip_runtime.h>
#include <hip/hip_bf16.h>
#include <math.h>

#define N_NODES 100000
#define N_EDGES 1600000
#define F_IN 512
#define HID 128
#define NCLS 40

typedef __attribute__((ext_vector_type(8))) short short8;
typedef __attribute__((ext_vector_type(4))) float floatx4;

__device__ __forceinline__ unsigned short f2bf(float x) {
    unsigned u = __builtin_bit_cast(unsigned, x);
    unsigned r = (u + 0x7FFFu + ((u >> 16) & 1u)) >> 16;   // RNE
    return (unsigned short)r;
}

// ---------------- utility ----------------

__global__ void k_zero_int(int* p, int n) {
    int i = blockIdx.x * blockDim.x + threadIdx.x;
    if (i < n) p[i] = 0;
}

// ---------------- degree / normalization ----------------

__global__ void k_count_deg(const int* __restrict__ dst, int* __restrict__ deg, int e) {
    int i = blockIdx.x * blockDim.x + threadIdx.x;
    if (i < e) atomicAdd(&deg[dst[i]], 1);
}

__global__ void k_inv(const int* __restrict__ deg, float* __restrict__ inv, int n) {
    int i = blockIdx.x * blockDim.x + threadIdx.x;
    if (i < n) inv[i] = rsqrtf((float)deg[i] + 1.0f);   // +1 self loop
}

// ---------------- exclusive scan (3-kernel) ----------------

#define SCAN_B 256

__global__ __launch_bounds__(SCAN_B) void k_scan1(const int* __restrict__ deg,
                                                  int* __restrict__ rp,
                                                  int* __restrict__ bsums, int n) {
    __shared__ int s[SCAN_B];
    int tid = threadIdx.x;
    int i = blockIdx.x * SCAN_B + tid;
    int v = (i < n) ? deg[i] : 0;
    s[tid] = v;
    __syncthreads();
    for (int off = 1; off < SCAN_B; off <<= 1) {
        int t = (tid >= off) ? s[tid - off] : 0;
        __syncthreads();
        s[tid] += t;
        __syncthreads();
    }
    if (i < n) rp[i] = s[tid] - v;                 // exclusive
    if (tid == SCAN_B - 1) bsums[blockIdx.x] = s[tid];
}

__global__ __launch_bounds__(512) void k_scan2(int* __restrict__ bsums, int nb) {
    __shared__ int s[512];
    int tid = threadIdx.x;
    int v = (tid < nb) ? bsums[tid] : 0;
    s[tid] = v;
    __syncthreads();
    for (int off = 1; off < 512; off <<= 1) {
        int t = (tid >= off) ? s[tid - off] : 0;
        __syncthreads();
        s[tid] += t;
        __syncthreads();
    }
    if (tid < nb) bsums[tid] = s[tid] - v;         // exclusive block offsets
}

__global__ void k_scan3(int* __restrict__ rp, const int* __restrict__ bsums, int n) {
    int i = blockIdx.x * SCAN_B + threadIdx.x;
    if (i < n) rp[i] += bsums[blockIdx.x];
}

// ---------------- CSR fill (counting sort by dst) ----------------

__global__ void k_fill(const int* __restrict__ src, const int* __restrict__ dst,
                       const int* __restrict__ rp, int* __restrict__ cursor,
                       int* __restrict__ csr_src, int e) {
    int i = blockIdx.x * blockDim.x + threadIdx.x;
    if (i >= e) return;
    int d = dst[i];
    int pos = atomicAdd(&cursor[d], 1);
    csr_src[rp[d] + pos] = src[i];
}

// ---------------- W1 transpose + bf16 convert: [512][128] -> [128][512] ------

__global__ __launch_bounds__(256) void k_w1t(const float* __restrict__ W1,
                                             unsigned short* __restrict__ W1t) {
    int idx = blockIdx.x * 256 + threadIdx.x;    // 65536
    int n = idx >> 9, k = idx & 511;
    W1t[idx] = f2bf(W1[k * HID + n]);
}

// ---------------- GEMM1 (MFMA bf16): h1 = x @ W1  [N,512]x[512,128] ----------
// 128x128 block tile, 4 waves, each 64x64 (4x4 of 16x16x32 MFMA), BK=32.
// LDS row stride 40 shorts (80 B): frag b128 reads hit all 32 banks 2-way (free).

#define GM 128

__global__ __launch_bounds__(256) void k_gemm1_mfma(
    const float* __restrict__ A,          // x [M,512] fp32
    const unsigned short* __restrict__ Bt, // W1t [128,512] bf16
    float* __restrict__ C,                // h1 [M,128] fp32
    int M)
{
    __shared__ unsigned short Asl[128 * 40];   // 10240 B
    __shared__ unsigned short Bsl[128 * 40];   // 10240 B

    const int tid  = threadIdx.x;
    const int wave = tid >> 6;
    const int lane = tid & 63;
    const int quad = lane >> 4;
    const int l15  = lane & 15;
    const int wm   = (wave >> 1) * 64;   // wave row offset in tile
    const int wn   = (wave & 1) * 64;    // wave col offset
    const int block_m = blockIdx.x * GM;

    floatx4 acc[4][4];
    #pragma unroll
    for (int i = 0; i < 4; ++i)
        #pragma unroll
        for (int j = 0; j < 4; ++j) acc[i][j] = (floatx4){0.f, 0.f, 0.f, 0.f};

    for (int k0 = 0; k0 < F_IN; k0 += 32) {
        // --- stage A tile: 128 rows x 32 k, fp32 -> bf16. 1024 float4, 4/thread.
        #pragma unroll
        for (int i = 0; i < 4; ++i) {
            int f  = tid + 256 * i;
            int r  = f >> 3;          // row in tile
            int kq = f & 7;           // float4 index within row (8 per row)
            int gr = block_m + r;
            gr = gr < M ? gr : M - 1; // clamp (rows >= M never stored)
            floatx4 v = *(const floatx4*)&A[(size_t)gr * F_IN + k0 + kq * 4];
            unsigned lo = (unsigned)f2bf(v.x) | ((unsigned)f2bf(v.y) << 16);
            unsigned hi = (unsigned)f2bf(v.z) | ((unsigned)f2bf(v.w) << 16);
            *(uint2*)&Asl[r * 40 + kq * 4] = make_uint2(lo, hi);
        }
        // --- stage B tile: 128 n-rows x 32 k, already bf16. 512 16B chunks, 2/thread.
        #pragma unroll
        for (int i = 0; i < 2; ++i) {
            int f  = tid + 256 * i;
            int r  = f >> 2;          // n row
            int kq = f & 3;           // 16B chunk within row (4 per row)
            int4 v = *(const int4*)&Bt[(size_t)r * F_IN + k0 + kq * 8];
            *(int4*)&Bsl[r * 40 + kq * 8] = v;
        }
        __syncthreads();

        short8 af[4], bf[4];
        #pragma unroll
        for (int t = 0; t < 4; ++t)
            af[t] = *(const short8*)&Asl[(wm + t * 16 + l15) * 40 + quad * 8];
        #pragma unroll
        for (int t = 0; t < 4; ++t)
            bf[t] = *(const short8*)&Bsl[(wn + t * 16 + l15) * 40 + quad * 8];

        #pragma unroll
        for (int tm = 0; tm < 4; ++tm)
            #pragma unroll
            for (int tn = 0; tn < 4; ++tn)
                acc[tm][tn] = __builtin_amdgcn_mfma_f32_16x16x32_bf16(
                    af[tm], bf[tn], acc[tm][tn], 0, 0, 0);
        __syncthreads();
    }

    // C/D layout: col = l15, row = quad*4 + reg
    #pragma unroll
    for (int tm = 0; tm < 4; ++tm) {
        #pragma unroll
        for (int r = 0; r < 4; ++r) {
            int row = block_m + wm + tm * 16 + quad * 4 + r;
            if (row < M) {
                #pragma unroll
                for (int tn = 0; tn < 4; ++tn)
                    C[(size_t)row * HID + wn + tn * 16 + l15] = acc[tm][tn][r];
            }
        }
    }
}

// ---------------- gather aggregation, layer 1 (fused self + bias + relu) ------
// one block of 128 threads per node; thread j = feature j

__global__ __launch_bounds__(128) void k_gather1(
    const float* __restrict__ h, const int* __restrict__ rp,
    const int* __restrict__ deg, const float* __restrict__ inv,
    const int* __restrict__ csr_src, const float* __restrict__ b1,
    float* __restrict__ out)
{
    __shared__ int   s_src[64];
    __shared__ float s_inv[64];
    const int node = blockIdx.x;
    const int j = threadIdx.x;
    const int start = rp[node];
    const int cnt = deg[node];

    float acc = 0.f;
    for (int base = 0; base < cnt; base += 64) {
        int m = min(64, cnt - base);
        __syncthreads();
        if (j < m) {
            int s = csr_src[start + base + j];
            s_src[j] = s;
            s_inv[j] = inv[s];
        }
        __syncthreads();
        for (int t = 0; t < m; ++t)
            acc += h[(size_t)s_src[t] * HID + j] * s_inv[t];
    }
    float invd = inv[node];
    float v = acc * invd + h[(size_t)node * HID + j] * invd * invd + b1[j];
    out[(size_t)node * HID + j] = fmaxf(v, 0.f);
}

// ---------------- GEMM2: h2 = hrelu @ W2  [N,128]x[128,40] ----------------

__global__ __launch_bounds__(256) void k_gemm2(
    const float* __restrict__ H, const float* __restrict__ W,
    float* __restrict__ OUT, int total)
{
    __shared__ float Ws[HID * NCLS];
    for (int i = threadIdx.x; i < HID * NCLS; i += 256) Ws[i] = W[i];
    __syncthreads();
    int idx = blockIdx.x * blockDim.x + threadIdx.x;
    if (idx >= total) return;
    unsigned node = (unsigned)idx / NCLS;
    unsigned j = (unsigned)idx - node * NCLS;
    const float* hrow = H + (long long)node * HID;
    float acc = 0.f;
    #pragma unroll 8
    for (int k = 0; k < HID; ++k) acc += hrow[k] * Ws[k * NCLS + j];
    OUT[idx] = acc;
}

// ------- gather aggregation, layer 2 (fused self + bias + log_softmax) -------

__global__ __launch_bounds__(256) void k_gather2(
    const float* __restrict__ h2, const int* __restrict__ rp,
    const int* __restrict__ deg, const float* __restrict__ inv,
    const int* __restrict__ csr_src, const float* __restrict__ b2,
    float* __restrict__ out)
{
    const int wave = threadIdx.x >> 6;
    const int lane = threadIdx.x & 63;
    const int node = blockIdx.x * 4 + wave;   // N divisible by 4
    const int start = rp[node];
    const int cnt = deg[node];
    const int j = lane;

    float acc = 0.f;
    for (int t = 0; t < cnt; ++t) {
        int s = csr_src[start + t];
        float c = inv[s];
        if (j < NCLS) acc += h2[(size_t)s * NCLS + j] * c;
    }
    float invd = inv[node];
    float v;
    if (j < NCLS)
        v = acc * invd + h2[(size_t)node * NCLS + j] * invd * invd + b2[j];
    else
        v = -INFINITY;

    float m = v;
    #pragma unroll
    for (int off = 32; off; off >>= 1) m = fmaxf(m, __shfl_down(m, off));
    m = __shfl(m, 0);
    float ex = (j < NCLS) ? __expf(v - m) : 0.f;
    float s2 = ex;
    #pragma unroll
    for (int off = 32; off; off >>= 1) s2 += __shfl_down(s2, off);
    s2 = __shfl(s2, 0);
    if (j < NCLS) out[(size_t)node * NCLS + j] = v - m - __logf(s2);
}

// ---------------- launch ----------------

extern "C" void kernel_launch(void* const* d_in, const int* in_sizes, int n_in,
                              void* d_out, int out_size, void* d_ws, size_t ws_size,
                              hipStream_t stream) {
    const float* x   = (const float*)d_in[0];
    const int*   ei  = (const int*)d_in[1];
    const float* W1  = (const float*)d_in[2];
    const float* b1  = (const float*)d_in[3];
    const float* W2  = (const float*)d_in[4];
    const float* b2  = (const float*)d_in[5];
    float* out = (float*)d_out;

    const int* src = ei;
    const int* dst = ei + N_EDGES;

    // workspace layout (4-byte units)
    char* wsb = (char*)d_ws;
    float* inv     = (float*)wsb;                                   // 131072
    float* h1      = inv + 131072;                                  // 12.8M (reused for h2)
    float* hrelu   = h1 + (size_t)N_NODES * HID;                    // 12.8M
    int*   deg     = (int*)(hrelu + (size_t)N_NODES * HID);         // 131072
    int*   rp      = deg + 131072;                                  // 131072
    int*   cursor  = rp + 131072;                                   // 131072 (dead after k_fill)
    int*   bsums   = cursor + 131072;                               // 1024
    int*   csr_src = bsums + 1024;                                  // 1.6M
    float* h2      = h1;                                            // alias (N*40)
    unsigned short* W1t = (unsigned short*)cursor;                  // reuse: 128K of 512K

    const int T = 256;
    const int NB = (N_NODES + SCAN_B - 1) / SCAN_B;   // 391

    // degree + normalization
    k_zero_int<<<(131072 * 2) / T, T, 0, stream>>>(deg, 131072 * 2);
    k_zero_int<<<131072 / T, T, 0, stream>>>(cursor, 131072);
    k_count_deg<<<N_EDGES / T, T, 0, stream>>>(dst, deg, N_EDGES);
    k_inv<<<NB, SCAN_B, 0, stream>>>(deg, inv, N_NODES);

    // CSR build
    k_scan1<<<NB, SCAN_B, 0, stream>>>(deg, rp, bsums, N_NODES);
    k_scan2<<<1, 512, 0, stream>>>(bsums, NB);
    k_scan3<<<NB, SCAN_B, 0, stream>>>(rp, bsums, N_NODES);
    k_fill<<<N_EDGES / T, T, 0, stream>>>(src, dst, rp, cursor, csr_src, N_EDGES);

    // W1 -> bf16 transposed (after k_fill: W1t reuses cursor's storage)
    k_w1t<<<(F_IN * HID) / T, T, 0, stream>>>(W1, W1t);

    // layer 1
    k_gemm1_mfma<<<(N_NODES + GM - 1) / GM, T, 0, stream>>>(x, W1t, h1, N_NODES);
    k_gather1<<<N_NODES, 128, 0, stream>>>(h1, rp, deg, inv, csr_src, b1, hrelu);

    // layer 2 (h2 aliases h1 — h1 dead after gather1)
    k_gemm2<<<(N_NODES * NCLS + T - 1) / T, T, 0, stream>>>(hrelu, W2, h2, N_NODES * NCLS);
    k_gather2<<<N_NODES / 4, T, 0, stream>>>(h2, rp, deg, inv, csr_src, b2, out);
}

// Round 5
// 677.515 us; speedup vs baseline: 3.0061x; 1.2453x over previous
//
#include <hip/hip_runtime.h>
#include <hip/hip_bf16.h>
#include <math.h>

#define N_NODES 100000
#define N_EDGES 1600000
#define F_IN 512
#define HID 128
#define NCLS 40

typedef __attribute__((ext_vector_type(8))) short short8;
typedef __attribute__((ext_vector_type(4))) float floatx4;

__device__ __forceinline__ unsigned short f2bf(float x) {
    unsigned u = __builtin_bit_cast(unsigned, x);
    unsigned r = (u + 0x7FFFu + ((u >> 16) & 1u)) >> 16;   // RNE
    return (unsigned short)r;
}
__device__ __forceinline__ float bflo(unsigned u) {
    return __builtin_bit_cast(float, u << 16);
}
__device__ __forceinline__ float bfhi(unsigned u) {
    return __builtin_bit_cast(float, u & 0xFFFF0000u);
}

// ---------------- utility ----------------

__global__ void k_zero_int(int* p, int n) {
    int i = blockIdx.x * blockDim.x + threadIdx.x;
    if (i < n) p[i] = 0;
}

// ---------------- degree / normalization ----------------

__global__ void k_count_deg(const int* __restrict__ dst, int* __restrict__ deg, int e) {
    int i = blockIdx.x * blockDim.x + threadIdx.x;
    if (i < e) atomicAdd(&deg[dst[i]], 1);
}

__global__ void k_inv(const int* __restrict__ deg, float* __restrict__ inv, int n) {
    int i = blockIdx.x * blockDim.x + threadIdx.x;
    if (i < n) inv[i] = rsqrtf((float)deg[i] + 1.0f);   // +1 self loop
}

// ---------------- exclusive scan (3-kernel) ----------------

#define SCAN_B 256

__global__ __launch_bounds__(SCAN_B) void k_scan1(const int* __restrict__ deg,
                                                  int* __restrict__ rp,
                                                  int* __restrict__ bsums, int n) {
    __shared__ int s[SCAN_B];
    int tid = threadIdx.x;
    int i = blockIdx.x * SCAN_B + tid;
    int v = (i < n) ? deg[i] : 0;
    s[tid] = v;
    __syncthreads();
    for (int off = 1; off < SCAN_B; off <<= 1) {
        int t = (tid >= off) ? s[tid - off] : 0;
        __syncthreads();
        s[tid] += t;
        __syncthreads();
    }
    if (i < n) rp[i] = s[tid] - v;                 // exclusive
    if (tid == SCAN_B - 1) bsums[blockIdx.x] = s[tid];
}

__global__ __launch_bounds__(512) void k_scan2(int* __restrict__ bsums, int nb) {
    __shared__ int s[512];
    int tid = threadIdx.x;
    int v = (tid < nb) ? bsums[tid] : 0;
    s[tid] = v;
    __syncthreads();
    for (int off = 1; off < 512; off <<= 1) {
        int t = (tid >= off) ? s[tid - off] : 0;
        __syncthreads();
        s[tid] += t;
        __syncthreads();
    }
    if (tid < nb) bsums[tid] = s[tid] - v;         // exclusive block offsets
}

__global__ void k_scan3(int* __restrict__ rp, const int* __restrict__ bsums, int n) {
    int i = blockIdx.x * SCAN_B + threadIdx.x;
    if (i < n) rp[i] += bsums[blockIdx.x];
}

// ---------------- CSR fill (counting sort by dst) ----------------

__global__ void k_fill(const int* __restrict__ src, const int* __restrict__ dst,
                       const int* __restrict__ rp, int* __restrict__ cursor,
                       int* __restrict__ csr_src, int e) {
    int i = blockIdx.x * blockDim.x + threadIdx.x;
    if (i >= e) return;
    int d = dst[i];
    int pos = atomicAdd(&cursor[d], 1);
    csr_src[rp[d] + pos] = src[i];
}

// ---------------- W1 transpose + bf16 convert: [512][128] -> [128][512] ------

__global__ __launch_bounds__(256) void k_w1t(const float* __restrict__ W1,
                                             unsigned short* __restrict__ W1t) {
    int idx = blockIdx.x * 256 + threadIdx.x;    // 65536
    int n = idx >> 9, k = idx & 511;
    W1t[idx] = f2bf(W1[k * HID + n]);
}

// ------- GEMM1 (MFMA bf16): h1s = (x @ W1) * inv[row], stored bf16 ----------
// 128x128 block tile, 4 waves, each 64x64 (4x4 of 16x16x32 MFMA), BK=32.

#define GM 128

__global__ __launch_bounds__(256) void k_gemm1_mfma(
    const float* __restrict__ A,            // x [M,512] fp32
    const unsigned short* __restrict__ Bt,  // W1t [128,512] bf16
    const float* __restrict__ inv,
    unsigned short* __restrict__ C,         // h1s [M,128] bf16
    int M)
{
    __shared__ unsigned short Asl[128 * 40];   // 10240 B
    __shared__ unsigned short Bsl[128 * 40];   // 10240 B

    const int tid  = threadIdx.x;
    const int wave = tid >> 6;
    const int lane = tid & 63;
    const int quad = lane >> 4;
    const int l15  = lane & 15;
    const int wm   = (wave >> 1) * 64;
    const int wn   = (wave & 1) * 64;
    const int block_m = blockIdx.x * GM;

    floatx4 acc[4][4];
    #pragma unroll
    for (int i = 0; i < 4; ++i)
        #pragma unroll
        for (int j = 0; j < 4; ++j) acc[i][j] = (floatx4){0.f, 0.f, 0.f, 0.f};

    for (int k0 = 0; k0 < F_IN; k0 += 32) {
        #pragma unroll
        for (int i = 0; i < 4; ++i) {
            int f  = tid + 256 * i;
            int r  = f >> 3;
            int kq = f & 7;
            int gr = block_m + r;
            gr = gr < M ? gr : M - 1;   // clamp (rows >= M never stored)
            floatx4 v = *(const floatx4*)&A[(size_t)gr * F_IN + k0 + kq * 4];
            unsigned lo = (unsigned)f2bf(v.x) | ((unsigned)f2bf(v.y) << 16);
            unsigned hi = (unsigned)f2bf(v.z) | ((unsigned)f2bf(v.w) << 16);
            *(uint2*)&Asl[r * 40 + kq * 4] = make_uint2(lo, hi);
        }
        #pragma unroll
        for (int i = 0; i < 2; ++i) {
            int f  = tid + 256 * i;
            int r  = f >> 2;
            int kq = f & 3;
            int4 v = *(const int4*)&Bt[(size_t)r * F_IN + k0 + kq * 8];
            *(int4*)&Bsl[r * 40 + kq * 8] = v;
        }
        __syncthreads();

        short8 af[4], bf[4];
        #pragma unroll
        for (int t = 0; t < 4; ++t)
            af[t] = *(const short8*)&Asl[(wm + t * 16 + l15) * 40 + quad * 8];
        #pragma unroll
        for (int t = 0; t < 4; ++t)
            bf[t] = *(const short8*)&Bsl[(wn + t * 16 + l15) * 40 + quad * 8];

        #pragma unroll
        for (int tm = 0; tm < 4; ++tm)
            #pragma unroll
            for (int tn = 0; tn < 4; ++tn)
                acc[tm][tn] = __builtin_amdgcn_mfma_f32_16x16x32_bf16(
                    af[tm], bf[tn], acc[tm][tn], 0, 0, 0);
        __syncthreads();
    }

    // C/D layout: col = l15, row = quad*4 + reg; fold inv[row], store bf16
    #pragma unroll
    for (int tm = 0; tm < 4; ++tm) {
        #pragma unroll
        for (int r = 0; r < 4; ++r) {
            int row = block_m + wm + tm * 16 + quad * 4 + r;
            if (row < M) {
                float iv = inv[row];
                #pragma unroll
                for (int tn = 0; tn < 4; ++tn)
                    C[(size_t)row * HID + wn + tn * 16 + l15] =
                        f2bf(acc[tm][tn][r] * iv);
            }
        }
    }
}

// ------- gather1: hrelu = relu(invd * (self + sum nbr h1s rows) + b1) -------
// one wave per node; lane = bf16x2 feature pair; 4-edge unroll

__global__ __launch_bounds__(256) void k_gather1(
    const unsigned* __restrict__ h1s,   // [N][64] uints (bf16x2)
    const int* __restrict__ rp, const int* __restrict__ deg,
    const float* __restrict__ inv, const int* __restrict__ csr_src,
    const float* __restrict__ b1, float* __restrict__ hrelu)
{
    const int wave = threadIdx.x >> 6;
    const int lane = threadIdx.x & 63;
    const int node = blockIdx.x * 4 + wave;   // N divisible by 4
    const int start = rp[node];
    const int cnt = deg[node];

    unsigned u = h1s[(size_t)node * 64 + lane];   // self row
    float acc0 = bflo(u), acc1 = bfhi(u);

    int t = 0;
    for (; t + 4 <= cnt; t += 4) {
        int s0 = csr_src[start + t + 0];
        int s1 = csr_src[start + t + 1];
        int s2 = csr_src[start + t + 2];
        int s3 = csr_src[start + t + 3];
        unsigned u0 = h1s[(size_t)s0 * 64 + lane];
        unsigned u1 = h1s[(size_t)s1 * 64 + lane];
        unsigned u2 = h1s[(size_t)s2 * 64 + lane];
        unsigned u3 = h1s[(size_t)s3 * 64 + lane];
        acc0 += (bflo(u0) + bflo(u1)) + (bflo(u2) + bflo(u3));
        acc1 += (bfhi(u0) + bfhi(u1)) + (bfhi(u2) + bfhi(u3));
    }
    for (; t < cnt; ++t) {
        int s = csr_src[start + t];
        unsigned uu = h1s[(size_t)s * 64 + lane];
        acc0 += bflo(uu);
        acc1 += bfhi(uu);
    }

    float invd = inv[node];
    float2 b = *(const float2*)&b1[lane * 2];
    float v0 = fmaxf(acc0 * invd + b.x, 0.f);
    float v1 = fmaxf(acc1 * invd + b.y, 0.f);
    *(float2*)&hrelu[(size_t)node * HID + lane * 2] = make_float2(v0, v1);
}

// ------- GEMM2: h2s = (hrelu @ W2) * inv[node], stored bf16 ----------------

__global__ __launch_bounds__(256) void k_gemm2(
    const float* __restrict__ H, const float* __restrict__ W,
    const float* __restrict__ inv, unsigned short* __restrict__ h2s)
{
    __shared__ float Ws[HID * NCLS];
    for (int i = threadIdx.x; i < HID * NCLS; i += 256) Ws[i] = W[i];
    __syncthreads();
    int idx = blockIdx.x * 256 + threadIdx.x;   // grid exact: N*40
    unsigned node = (unsigned)idx / NCLS;
    unsigned j = (unsigned)idx - node * NCLS;
    const float* hrow = H + (size_t)node * HID;
    float acc = 0.f;
    #pragma unroll 8
    for (int k = 0; k < HID; ++k) acc += hrow[k] * Ws[k * NCLS + j];
    h2s[idx] = f2bf(acc * inv[node]);
}

// ------- gather2: fused aggregation + bias + log_softmax -------------------
// one wave per node; lanes = 3 edge-groups x 20 bf16x2 feature pairs

__global__ __launch_bounds__(256) void k_gather2(
    const unsigned* __restrict__ h2s,   // [N][20] uints (bf16x2)
    const int* __restrict__ rp, const int* __restrict__ deg,
    const float* __restrict__ inv, const int* __restrict__ csr_src,
    const float* __restrict__ b2, float* __restrict__ out)
{
    const int wave = threadIdx.x >> 6;
    const int lane = threadIdx.x & 63;
    const int node = blockIdx.x * 4 + wave;   // N divisible by 4
    const int g = lane / 20;                  // 0,1,2 active; 3 idle
    const int j = lane - g * 20;              // feature pair 0..19
    const int start = rp[node];
    const int cnt = deg[node];

    float acc0 = 0.f, acc1 = 0.f;
    if (g == 0) {                             // self row
        unsigned u = h2s[(size_t)node * 20 + j];
        acc0 = bflo(u);
        acc1 = bfhi(u);
    }
    if (g < 3) {
        int t = g;
        for (; t + 3 < cnt; t += 6) {         // 2 edges per iter per group
            int s0 = csr_src[start + t];
            int s1 = csr_src[start + t + 3];
            unsigned u0 = h2s[(size_t)s0 * 20 + j];
            unsigned u1 = h2s[(size_t)s1 * 20 + j];
            acc0 += bflo(u0) + bflo(u1);
            acc1 += bfhi(u0) + bfhi(u1);
        }
        if (t < cnt) {
            int s = csr_src[start + t];
            unsigned u = h2s[(size_t)s * 20 + j];
            acc0 += bflo(u);
            acc1 += bfhi(u);
        }
    }
    // fold edge-groups 1,2 into group 0 (bpermute reads lanes j+20, j+40)
    acc0 += __shfl(acc0, j + 20) + __shfl(acc0, j + 40);
    acc1 += __shfl(acc1, j + 20) + __shfl(acc1, j + 40);

    float invd = inv[node];
    float v0 = -INFINITY, v1 = -INFINITY;
    if (g == 0) {
        float2 b = *(const float2*)&b2[j * 2];
        v0 = acc0 * invd + b.x;
        v1 = acc1 * invd + b.y;
    }
    float m = fmaxf(v0, v1);
    #pragma unroll
    for (int mask = 16; mask; mask >>= 1) m = fmaxf(m, __shfl_xor(m, mask));
    float e = (g == 0) ? (__expf(v0 - m) + __expf(v1 - m)) : 0.f;
    #pragma unroll
    for (int mask = 16; mask; mask >>= 1) e += __shfl_xor(e, mask);
    if (g == 0) {
        float lg = __logf(e);
        *(float2*)&out[(size_t)node * NCLS + j * 2] =
            make_float2(v0 - m - lg, v1 - m - lg);
    }
}

// ---------------- launch ----------------

extern "C" void kernel_launch(void* const* d_in, const int* in_sizes, int n_in,
                              void* d_out, int out_size, void* d_ws, size_t ws_size,
                              hipStream_t stream) {
    const float* x   = (const float*)d_in[0];
    const int*   ei  = (const int*)d_in[1];
    const float* W1  = (const float*)d_in[2];
    const float* b1  = (const float*)d_in[3];
    const float* W2  = (const float*)d_in[4];
    const float* b2  = (const float*)d_in[5];
    float* out = (float*)d_out;

    const int* src = ei;
    const int* dst = ei + N_EDGES;

    // workspace layout (4-byte units; slot sizes unchanged from R3)
    char* wsb = (char*)d_ws;
    float* inv      = (float*)wsb;                                  // 131072
    float* slot1    = inv + 131072;                                 // 12.8M floats
    float* hrelu    = slot1 + (size_t)N_NODES * HID;                // 12.8M floats
    int*   deg      = (int*)(hrelu + (size_t)N_NODES * HID);        // 131072
    int*   rp       = deg + 131072;                                 // 131072
    int*   cursor   = rp + 131072;                                  // 131072 (dead after k_fill)
    int*   bsums    = cursor + 131072;                              // 1024
    int*   csr_src  = bsums + 1024;                                 // 1.6M
    unsigned short* h1s_st = (unsigned short*)slot1;                // N*128 bf16 (store view)
    unsigned short* h2s_st = (unsigned short*)slot1;                // N*40 bf16 (store view)
    unsigned* h1s_ld = (unsigned*)slot1;                            // packed bf16x2 load view
    unsigned* h2s_ld = (unsigned*)slot1;                            // packed bf16x2 load view
    unsigned short* W1t = (unsigned short*)cursor;                  // reuse after k_fill

    const int T = 256;
    const int NB = (N_NODES + SCAN_B - 1) / SCAN_B;   // 391

    // degree + normalization
    k_zero_int<<<(131072 * 2) / T, T, 0, stream>>>(deg, 131072 * 2);
    k_zero_int<<<131072 / T, T, 0, stream>>>(cursor, 131072);
    k_count_deg<<<N_EDGES / T, T, 0, stream>>>(dst, deg, N_EDGES);
    k_inv<<<NB, SCAN_B, 0, stream>>>(deg, inv, N_NODES);

    // CSR build
    k_scan1<<<NB, SCAN_B, 0, stream>>>(deg, rp, bsums, N_NODES);
    k_scan2<<<1, 512, 0, stream>>>(bsums, NB);
    k_scan3<<<NB, SCAN_B, 0, stream>>>(rp, bsums, N_NODES);
    k_fill<<<N_EDGES / T, T, 0, stream>>>(src, dst, rp, cursor, csr_src, N_EDGES);

    // W1 -> bf16 transposed (after k_fill: W1t reuses cursor's storage)
    k_w1t<<<(F_IN * HID) / T, T, 0, stream>>>(W1, W1t);

    // layer 1
    k_gemm1_mfma<<<(N_NODES + GM - 1) / GM, T, 0, stream>>>(x, W1t, inv, h1s_st, N_NODES);
    k_gather1<<<N_NODES / 4, T, 0, stream>>>(h1s_ld, rp, deg, inv, csr_src, b1, hrelu);

    // layer 2 (h2s aliases h1s — dead after gather1)
    k_gemm2<<<(N_NODES * NCLS) / T, T, 0, stream>>>(hrelu, W2, inv, h2s_st);
    k_gather2<<<N_NODES / 4, T, 0, stream>>>(h2s_ld, rp, deg, inv, csr_src, b2, out);
}